// Round 3
// baseline (133.522 us; speedup 1.0000x reference)
//
#include <hip/hip_runtime.h>
#include <hip/hip_fp16.h>

// Problem constants (B,C,D,H,W) = (2,4,96,160,160)
#define NB 2
#define NC 4
#define ND 96
#define NH 160
#define NW 160

// Math (verified exact rounds 1-7): sy == sz (identical 2D 3x3 kernels),
// depth padding contributes only zero slices, and kernel depth-extent is 1 so
// conv output H,W = 160 exactly (H_pad-3+1) -> only rows/cols 0..159 emit.
// sobel(p)-sobel(t) = sobel(q), q = softmax(pred) - onehot(target):
//   loss = sum(gx^2 + 2*gy^2) * SCALE
// separable: d = q[x+1]-q[x-1], s = q[x-1]+2q[x]+q[x+1],
//            gx = d[y-1]+2d[y]+d[y+1], gy = s[y+1]-s[y-1].
//
// Perf history:
//  r4/r5: __launch_bounds__(256,N) VGPR cap -> 128 MB scratch spill. NEVER
//         add an occupancy floor here.
//  r2..r6: same-address atomicAdds serialize cross-XCD (~20ns each). NEVER
//         one-atomic-per-block; plain per-block stores + tiny reduce kernel.
//  r8:    barrier-phased LDS-tile kernel: ~28-30us (vs ~18us stream floor).
//  r9:    -10MB halo bytes + XCD swizzle: NEUTRAL. Bytes/L2 not binding.
//  r10:   reg-prefetch pipeline inside barrier structure: -2.3us REGRESSION
//         (prefetch regs live across Sobel -> VGPR >128 -> 2 waves/SIMD).
//  r11 (this): timed region = 2x300MiB harness poison fills (~94us,
//         untouchable) + ours. Diagnosis: barrier-phased blocks serialize
//         mem phase (6.3us/CU-gen) and compute phase (1.6us/CU-gen) in ~3
//         lockstep generations -> ~28us. Fix: REMOVE the phase structure.
//         Wave-autonomous rolling-column stencil: no LDS, no __syncthreads;
//         lane = 2 adjacent cols, 5 small loads + ~80 VALU per row-iter,
//         one-row-ahead double buffer, x-neighbors via __shfl, vertical
//         Sobel rolled in registers. VMEM issue is continuous per wave; 6144
//         independent waves drift freely and hide each other's latency.
constexpr int ROWS   = 10;             // output rows per wave-task
constexpr int NBANDV = NH / ROWS;      // 16 bands
constexpr int NSTRIP = 2;              // col strips: [0..127] out 0..126,
                                       //             [126..253] out 127..159
constexpr int NTASK  = NSTRIP * NBANDV * NB * ND;  // 6144 wave-tasks
constexpr int NBLK   = NTASK / 4;      // 1536 blocks of 256 (4 waves/block)
constexpr float SCALE = 1.0f / (2.0f * 98.0f * 162.0f * 162.0f * 4.0f);

__device__ __forceinline__ __half2 shfl_h2(__half2 v, int src) {
    return __builtin_bit_cast(
        __half2, __shfl(__builtin_bit_cast(unsigned int, v), src, 64));
}

// One pixel: softmax over 4 class logits minus onehot(target), packed as
// two half2 (classes 01 -> qa, classes 23 -> qb). valid=false -> q = 0
// (zero-padding rows/cols and out-of-image lanes).
__device__ __forceinline__ void qcalc2(float p0, float p1, float p2, float p3,
                                       int t, bool valid,
                                       __half2& qa, __half2& qb) {
    float q0 = 0.f, q1 = 0.f, q2 = 0.f, q3 = 0.f;
    if (valid) {
        const float m  = fmaxf(fmaxf(p0, p1), fmaxf(p2, p3));
        const float e0 = __expf(p0 - m);
        const float e1 = __expf(p1 - m);
        const float e2 = __expf(p2 - m);
        const float e3 = __expf(p3 - m);
        const float inv = 1.0f / (e0 + e1 + e2 + e3);
        q0 = e0 * inv - (t == 0 ? 1.f : 0.f);
        q1 = e1 * inv - (t == 1 ? 1.f : 0.f);
        q2 = e2 * inv - (t == 2 ? 1.f : 0.f);
        q3 = e3 * inv - (t == 3 ? 1.f : 0.f);
    }
    qa = __floats2half2_rn(q0, q1);
    qb = __floats2half2_rn(q2, q3);
}

__global__ __launch_bounds__(256) void boundary_loss_kernel(
    const float* __restrict__ pred,   // (B,C,D,H,W) f32
    const int*   __restrict__ target, // (B,D,H,W) i32
    float* __restrict__ part)         // NTASK per-wave partials
{
    const int tid  = threadIdx.x;
    const int lane = tid & 63;
    const int task = blockIdx.x * 4 + (tid >> 6);   // 4 independent waves
    const int strip = task & 1;
    const int band  = (task >> 1) & (NBANDV - 1);
    const int slice = task >> 5;                    // b*ND + d, 0..191
    const int b     = slice / ND;
    const int d     = slice - b * ND;
    const int y0    = band * ROWS;

    // Column geometry: lane owns even col ce and odd col ce+1.
    const int  ce = strip * 126 + 2 * lane;
    const int  cc = min(ce, NW - 2);        // aligned, clamped load col
    const bool vE = ce < NW;                // in-image masks (q=0 outside)
    const bool vO = (ce + 1) < NW;
    const int  outLo = strip ? 127 : 0;     // output ownership (no overlap)
    const int  outHi = strip ? 159 : 126;
    const bool oE = (ce >= outLo) && (ce <= outHi);
    const bool oO = (ce + 1 >= outLo) && (ce + 1 <= outHi);

    const size_t plane = (size_t)NH * NW;
    const float* pc0 = pred + ((size_t)(b * NC + 0) * ND + d) * plane;
    const float* pc1 = pred + ((size_t)(b * NC + 1) * ND + d) * plane;
    const float* pc2 = pred + ((size_t)(b * NC + 2) * ND + d) * plane;
    const float* pc3 = pred + ((size_t)(b * NC + 3) * ND + d) * plane;
    const int*   tg0 = target + ((size_t)b * ND + d) * plane;

    const int upL = (lane == 0)  ? 0  : lane - 1;   // clamped shuffle lanes;
    const int dnL = (lane == 63) ? 63 : lane + 1;   // garbage only feeds
                                                    // masked outputs
    const bool killL = (strip == 0) && (lane == 0); // col -1 must be q=0

    const __half2 two = __floats2half2_rn(2.f, 2.f);
    const __half2 hz  = __floats2half2_rn(0.f, 0.f);

    // Rolling vertical state: s(t-2),s(t-1),d(t-2),d(t-1) per plane/parity.
    __half2 sAe2 = hz, sAe1 = hz, dAe2 = hz, dAe1 = hz;
    __half2 sAo2 = hz, sAo1 = hz, dAo2 = hz, dAo1 = hz;
    __half2 sBe2 = hz, sBe1 = hz, dBe2 = hz, dBe1 = hz;
    __half2 sBo2 = hz, sBo1 = hz, dBo2 = hz, dBo1 = hz;
    float accE = 0.f, accO = 0.f;

    // One-row-ahead double buffer (indices compile-time after full unroll).
    float2 L0[2], L1[2], L2[2], L3[2]; int2 LT[2];

    auto issue = [&](int t, int buf) {
        const int y  = y0 - 1 + t;
        const int yc = min(max(y, 0), NH - 1);
        const size_t ro = (size_t)yc * NW + cc;
        L0[buf] = *(const float2*)(pc0 + ro);
        L1[buf] = *(const float2*)(pc1 + ro);
        L2[buf] = *(const float2*)(pc2 + ro);
        L3[buf] = *(const float2*)(pc3 + ro);
        LT[buf] = *(const int2*)(tg0 + ro);
    };

    issue(0, 0);
    #pragma unroll
    for (int t = 0; t < ROWS + 2; ++t) {
        const int cur = t & 1;
        if (t + 1 < ROWS + 2) issue(t + 1, cur ^ 1);  // prefetch next row

        const int  y  = y0 - 1 + t;
        const bool vy = (y >= 0) && (y < NH);         // wave-uniform

        __half2 qaE, qbE, qaO, qbO;
        qcalc2(L0[cur].x, L1[cur].x, L2[cur].x, L3[cur].x, LT[cur].x,
               vy && vE, qaE, qbE);
        qcalc2(L0[cur].y, L1[cur].y, L2[cur].y, L3[cur].y, LT[cur].y,
               vy && vO, qaO, qbO);

        // x-neighbor exchange: even col's left = lane-1's odd; odd col's
        // right = lane+1's even.
        __half2 qaU = shfl_h2(qaO, upL); if (killL) qaU = hz;
        __half2 qbU = shfl_h2(qbO, upL); if (killL) qbU = hz;
        __half2 qaD = shfl_h2(qaE, dnL);
        __half2 qbD = shfl_h2(qbE, dnL);

        // Horizontal smooth s and diff d for both parities, both planes.
        const __half2 sAe = __hadd2(__hfma2(qaE, two, qaU), qaO);
        const __half2 dAe = __hsub2(qaO, qaU);
        const __half2 sAo = __hadd2(__hfma2(qaO, two, qaE), qaD);
        const __half2 dAo = __hsub2(qaD, qaE);
        const __half2 sBe = __hadd2(__hfma2(qbE, two, qbU), qbO);
        const __half2 dBe = __hsub2(qbO, qbU);
        const __half2 sBo = __hadd2(__hfma2(qbO, two, qbE), qbD);
        const __half2 dBo = __hsub2(qbD, qbE);

        if (t >= 2) {   // emit output row y-1
            {
                const __half2 gx = __hadd2(__hfma2(dAe1, two, dAe2), dAe);
                const __half2 gy = __hsub2(sAe, sAe2);
                const __half2 rs = __hfma2(__hmul2(gy, gy), two,
                                           __hmul2(gx, gx));
                accE += __low2float(rs) + __high2float(rs);
            }
            {
                const __half2 gx = __hadd2(__hfma2(dBe1, two, dBe2), dBe);
                const __half2 gy = __hsub2(sBe, sBe2);
                const __half2 rs = __hfma2(__hmul2(gy, gy), two,
                                           __hmul2(gx, gx));
                accE += __low2float(rs) + __high2float(rs);
            }
            {
                const __half2 gx = __hadd2(__hfma2(dAo1, two, dAo2), dAo);
                const __half2 gy = __hsub2(sAo, sAo2);
                const __half2 rs = __hfma2(__hmul2(gy, gy), two,
                                           __hmul2(gx, gx));
                accO += __low2float(rs) + __high2float(rs);
            }
            {
                const __half2 gx = __hadd2(__hfma2(dBo1, two, dBo2), dBo);
                const __half2 gy = __hsub2(sBo, sBo2);
                const __half2 rs = __hfma2(__hmul2(gy, gy), two,
                                           __hmul2(gx, gx));
                accO += __low2float(rs) + __high2float(rs);
            }
        }
        sAe2 = sAe1; sAe1 = sAe; dAe2 = dAe1; dAe1 = dAe;
        sAo2 = sAo1; sAo1 = sAo; dAo2 = dAo1; dAo1 = dAo;
        sBe2 = sBe1; sBe1 = sBe; dBe2 = dBe1; dBe1 = dBe;
        sBo2 = sBo1; sBo1 = sBo; dBo2 = dBo1; dBo1 = dBo;
    }

    // Ownership masks fold in once at the end (loop-invariant).
    float acc = (oE ? accE : 0.f) + (oO ? accO : 0.f);

    // Per-wave reduction -> ONE PLAIN STORE per wave (no atomics, no LDS).
    #pragma unroll
    for (int off = 32; off > 0; off >>= 1)
        acc += __shfl_down(acc, off, 64);
    if (lane == 0) part[task] = acc;
}

__global__ __launch_bounds__(256) void reduce_partials_kernel(
    const float* __restrict__ part, float* __restrict__ out)
{
    const int tid = threadIdx.x;
    const float4* p4 = (const float4*)part;   // NTASK/4 = 1536 float4
    float s = 0.f;
    #pragma unroll
    for (int i = 0; i < NTASK / 1024; ++i) {  // 6 coalesced b128 loads
        const float4 v = p4[tid + i * 256];
        s += (v.x + v.y) + (v.z + v.w);
    }
    #pragma unroll
    for (int off = 32; off > 0; off >>= 1)
        s += __shfl_down(s, off, 64);
    __shared__ float wsum[4];
    if ((tid & 63) == 0) wsum[tid >> 6] = s;
    __syncthreads();
    if (tid == 0)
        out[0] = (wsum[0] + wsum[1] + wsum[2] + wsum[3]) * SCALE;
}

extern "C" void kernel_launch(void* const* d_in, const int* in_sizes, int n_in,
                              void* d_out, int out_size, void* d_ws, size_t ws_size,
                              hipStream_t stream) {
    const float* pred   = (const float*)d_in[0];
    const int*   target = (const int*)d_in[1];
    float*       out    = (float*)d_out;
    float*       part   = (float*)d_ws;      // NTASK*4 = 24 KB of scratch

    boundary_loss_kernel<<<dim3(NBLK), 256, 0, stream>>>(pred, target, part);
    reduce_partials_kernel<<<1, 256, 0, stream>>>(part, out);
}

// Round 4
// 128.778 us; speedup vs baseline: 1.0368x; 1.0368x over previous
//
#include <hip/hip_runtime.h>
#include <hip/hip_fp16.h>

// Problem constants (B,C,D,H,W) = (2,4,96,160,160)
#define NB 2
#define NC 4
#define ND 96
#define NH 160
#define NW 160

// Math (verified exact rounds 1-7): sy == sz (identical 2D 3x3 kernels),
// depth padding adds only zero slices, sobel(p)-sobel(t) = sobel(q) with
// q = softmax(pred) - onehot(target):
//   loss = sum(gx^2 + 2*gy^2) * SCALE
// separable: d = q[x+1]-q[x-1], s = q[x-1]+2q[x]+q[x+1],
//            gx = d[y-1]+2d[y]+d[y+1], gy = s[y+1]-s[y-1].
//
// Perf history (two sessions):
//  r4/r5: __launch_bounds__(256,N) VGPR cap -> 128 MB scratch spill. NEVER
//         add an occupancy floor here.
//  r2..r6: same-address atomicAdds serialize cross-XCD (~20ns each). NEVER
//         one-atomic-per-block; plain per-block stores + tiny reduce kernel.
//  r8:    THIS kernel. 128.1 / 129.4 us across two sessions. Best measured.
//  r9:    TH 8->10 (-10 MB halo) + XCD-chunked swizzle: NEUTRAL (130.3).
//  r10:   in-block reg-prefetch pipeline: REGRESSION (132.6; prefetch regs
//         live across Sobel -> VGPR pressure).
//  r11:   wave-autonomous no-LDS no-barrier rolling stencil: NEUTRAL-WORSE
//         (133.5).
//  CEILING ANALYSIS (r12): timed region = 2 x 300MiB harness poison fills
//  (deliberate L3 flushers, 2x47us = 94.5us, serialized on stream,
//  untouchable) + boundary (~28us vs ~19us cold-HBM stream floor) + reduce
//  + graph gaps (~6us). Four structurally distinct boundary kernels
//  (barrier-LDS-tile / byte-reduced / pipelined / wave-autonomous) all land
//  129.4-133.5us: bytes, L2 locality, occupancy, and VMEM-issue continuity
//  are each individually non-binding. Practical floor ~129us == this kernel.
constexpr int TH    = 8;              // output rows per band
constexpr int SR    = TH + 2;         // staged rows (vertical halo)
constexpr int NBAND = NH / TH;        // 20 bands per slice
constexpr int NSLOT = SR * NW / 4;    // 400 4-pixel staging slots
constexpr int PCELL = SR * NW;        // 1600 px cells per plane
constexpr int ZCELL = PCELL;          // always-zero guard cell (x-boundary)
constexpr int NPART = NBAND * NB * ND;           // 3840 partials
constexpr float SCALE = 1.0f / (2.0f * 98.0f * 162.0f * 162.0f * 4.0f);

__device__ __forceinline__ __half2 ld_h2(const unsigned int* p, int i) {
    return __builtin_bit_cast(__half2, p[i]);
}

// One pixel: softmax over 4 class logits minus onehot(target), packed as
// two half2 (classes 01 -> a, classes 23 -> b).
__device__ __forceinline__ void qcalc(float p0, float p1, float p2, float p3,
                                      int t, bool valid,
                                      unsigned int& ha, unsigned int& hb) {
    float q0 = 0.f, q1 = 0.f, q2 = 0.f, q3 = 0.f;
    if (valid) {
        const float m  = fmaxf(fmaxf(p0, p1), fmaxf(p2, p3));
        const float e0 = __expf(p0 - m);
        const float e1 = __expf(p1 - m);
        const float e2 = __expf(p2 - m);
        const float e3 = __expf(p3 - m);
        const float inv = 1.0f / (e0 + e1 + e2 + e3);
        q0 = e0 * inv - (t == 0 ? 1.f : 0.f);
        q1 = e1 * inv - (t == 1 ? 1.f : 0.f);
        q2 = e2 * inv - (t == 2 ? 1.f : 0.f);
        q3 = e3 * inv - (t == 3 ? 1.f : 0.f);
    }
    ha = __builtin_bit_cast(unsigned int, __floats2half2_rn(q0, q1));
    hb = __builtin_bit_cast(unsigned int, __floats2half2_rn(q2, q3));
}

__global__ __launch_bounds__(256) void boundary_loss_kernel(
    const float* __restrict__ pred,   // (B,C,D,H,W) f32
    const int*   __restrict__ target, // (B,D,H,W) i32
    float* __restrict__ part)         // NPART per-block partials
{
    __shared__ unsigned int pa[PCELL + 4];  // classes 0,1 packed half2
    __shared__ unsigned int pb[PCELL + 4];  // classes 2,3 packed half2
    __shared__ float wsum[4];

    const int tid   = threadIdx.x;
    const int slice = blockIdx.y;     // b*ND + d
    const int b     = slice / ND;
    const int d     = slice - b * ND;
    const int y0    = blockIdx.x * TH;

    const size_t cs4   = (size_t)ND * NH * NW / 4;   // class stride in float4
    const size_t pbase = ((size_t)b * NC * ND + d) * (size_t)(NH * NW);
    const size_t tbase = ((size_t)b * ND + d) * (size_t)(NH * NW);

    // ---- Load phase: slot A = tid, slot B = tid + 256 (tid < 144) ----
    const int  rA   = tid / 40;
    const int  cA   = tid - rA * 40;
    const int  gyA  = y0 - 1 + rA;
    const bool vA   = (gyA >= 0) && (gyA < NH);
    const int  gyAc = min(max(gyA, 0), NH - 1);

    const int  sB   = tid + 256;
    const bool hasB = (sB < NSLOT);
    const int  rB   = sB / 40;
    const int  cB   = sB - rB * 40;
    const int  gyB  = y0 - 1 + rB;
    const bool vB   = hasB && (gyB >= 0) && (gyB < NH);
    const int  gyBc = min(max(gyB, 0), NH - 1);

    // All loads into named registers, issued back-to-back (one latency
    // exposure); default VGPR budget keeps them resident (no scratch).
    const float4* ppA = (const float4*)(pred + pbase + (size_t)gyAc * NW) + cA;
    const float4 a0 = ppA[0];
    const float4 a1 = ppA[cs4];
    const float4 a2 = ppA[2 * cs4];
    const float4 a3 = ppA[3 * cs4];
    const int4   ta = ((const int4*)(target + tbase + (size_t)gyAc * NW))[cA];

    const int cBs  = hasB ? cB : 0;   // safe address for inactive threads
    const int gyBs = hasB ? gyBc : 0;
    const float4* ppB = (const float4*)(pred + pbase + (size_t)gyBs * NW) + cBs;
    const float4 b0 = ppB[0];
    const float4 b1 = ppB[cs4];
    const float4 b2 = ppB[2 * cs4];
    const float4 b3 = ppB[3 * cs4];
    const int4   tb = ((const int4*)(target + tbase + (size_t)gyBs * NW))[cBs];

    // ---- Softmax + pack + stage: one b128 per plane per slot ----
    {
        uint4 wa, wb;
        qcalc(a0.x, a1.x, a2.x, a3.x, ta.x, vA, wa.x, wb.x);
        qcalc(a0.y, a1.y, a2.y, a3.y, ta.y, vA, wa.y, wb.y);
        qcalc(a0.z, a1.z, a2.z, a3.z, ta.z, vA, wa.z, wb.z);
        qcalc(a0.w, a1.w, a2.w, a3.w, ta.w, vA, wa.w, wb.w);
        ((uint4*)pa)[rA * 40 + cA] = wa;   // 16-B lane stride: conflict-free
        ((uint4*)pb)[rA * 40 + cA] = wb;
    }
    if (hasB) {
        uint4 wa, wb;
        qcalc(b0.x, b1.x, b2.x, b3.x, tb.x, vB, wa.x, wb.x);
        qcalc(b0.y, b1.y, b2.y, b3.y, tb.y, vB, wa.y, wb.y);
        qcalc(b0.z, b1.z, b2.z, b3.z, tb.z, vB, wa.z, wb.z);
        qcalc(b0.w, b1.w, b2.w, b3.w, tb.w, vB, wa.w, wb.w);
        ((uint4*)pa)[rB * 40 + cB] = wa;
        ((uint4*)pb)[rB * 40 + cB] = wb;
    }
    if (tid == 0) { pa[ZCELL] = 0u; pb[ZCELL] = 0u; }  // x-boundary guard
    __syncthreads();

    // ---- Vertical rolling Sobel (packed half2): column x = tid < 160 ----
    float acc = 0.f;
    if (tid < NW) {
        // branchless rolling addresses; boundary lanes pin l/r to ZCELL
        int am = tid;
        int al = (tid > 0)      ? tid - 1 : ZCELL;
        int ar = (tid < NW - 1) ? tid + 1 : ZCELL;
        const int il = (tid > 0)      ? NW : 0;
        const int ir = (tid < NW - 1) ? NW : 0;

        const __half2 two = __floats2half2_rn(2.f, 2.f);
        const __half2 hz  = __floats2half2_rn(0.f, 0.f);
        __half2 smmA = hz, smA = hz, dmmA = hz, dmA = hz;
        __half2 smmB = hz, smB = hz, dmmB = hz, dmB = hz;

#define CLS(P, smm, sm, dmm, dm)                                          \
        do {                                                              \
            const __half2 l = ld_h2(P, al);                               \
            const __half2 m = ld_h2(P, am);                               \
            const __half2 r = ld_h2(P, ar);                               \
            const __half2 sn = __hadd2(__hfma2(m, two, l), r);            \
            const __half2 dn = __hsub2(r, l);                             \
            if (t >= 2) {                                                 \
                const __half2 gx = __hadd2(__hfma2(dm, two, dmm), dn);    \
                const __half2 gy = __hsub2(sn, smm);                      \
                const __half2 rs = __hfma2(__hmul2(gy, gy), two,          \
                                           __hmul2(gx, gx));              \
                acc += __low2float(rs) + __high2float(rs);                \
            }                                                             \
            smm = sm; sm = sn; dmm = dm; dm = dn;                         \
        } while (0)

        #pragma unroll
        for (int t = 0; t < SR; ++t) {
            CLS(pa, smmA, smA, dmmA, dmA);
            CLS(pb, smmB, smB, dmmB, dmB);
            am += NW; al += il; ar += ir;
        }
#undef CLS
    }

    // ---- Block reduction -> ONE PLAIN STORE per block (no atomics) ----
    #pragma unroll
    for (int off = 32; off > 0; off >>= 1)
        acc += __shfl_down(acc, off, 64);
    if ((tid & 63) == 0) wsum[tid >> 6] = acc;
    __syncthreads();
    if (tid == 0) {
        part[blockIdx.y * NBAND + blockIdx.x] =
            wsum[0] + wsum[1] + wsum[2] + wsum[3];
    }
}

__global__ __launch_bounds__(256) void reduce_partials_kernel(
    const float* __restrict__ part, float* __restrict__ out)
{
    const int tid = threadIdx.x;
    float s = 0.f;
    #pragma unroll
    for (int i = 0; i < NPART / 256; ++i)     // 15 loads, coalesced
        s += part[tid + i * 256];
    #pragma unroll
    for (int off = 32; off > 0; off >>= 1)
        s += __shfl_down(s, off, 64);
    __shared__ float wsum[4];
    if ((tid & 63) == 0) wsum[tid >> 6] = s;
    __syncthreads();
    if (tid == 0)
        out[0] = (wsum[0] + wsum[1] + wsum[2] + wsum[3]) * SCALE;
}

extern "C" void kernel_launch(void* const* d_in, const int* in_sizes, int n_in,
                              void* d_out, int out_size, void* d_ws, size_t ws_size,
                              hipStream_t stream) {
    const float* pred   = (const float*)d_in[0];
    const int*   target = (const int*)d_in[1];
    float*       out    = (float*)d_out;
    float*       part   = (float*)d_ws;      // NPART*4 = 15 KB of scratch

    dim3 grid(NBAND, NB * ND);   // 20 x 192 = 3840 blocks
    boundary_loss_kernel<<<grid, 256, 0, stream>>>(pred, target, part);
    reduce_partials_kernel<<<1, 256, 0, stream>>>(part, out);
}